// Round 16
// baseline (55.295 us; speedup 1.0000x reference)
//
#include <hip/hip_runtime.h>
#include <cmath>

// Local contrast normalization, fused tile kernel — static-sweep version.
// x: [64,512,512,1] f32. 9x9 Gaussian (separable, center 4.5), SAME zero pad.
// Tile: 64 wide x 32 tall, 256 threads, 25.3 KB LDS (6 blocks/CU).
// r16: every phase is STATIC straight-line sweeps + predicated tail
// (dynamic `for (t=tid; t<N; t+=256)` loops serialized loads per
// iteration; static unroll lets the scheduler batch them). Interior
// blocks (66%) additionally run guard-free (r15).

struct W9 { float w[9]; };

typedef float nf4 __attribute__((ext_vector_type(4)));  // nontemporal store

#define HW   512
#define HW4  128   // f4 per image row
#define TSY  32    // output tile height
#define NH1  18    // h1/dd width in f4 (72 cols: ox-4 .. ox+67)
#define NH2  16    // h2/out width in f4 (64 cols)
#define RH1  48    // h1 rows  (oy-8 .. oy+39)
#define RDD  40    // dd/h2 rows (oy-4 .. oy+35)

__device__ __forceinline__ float4 conv9(const float* X, const float* w) {
    float4 o = {0.f, 0.f, 0.f, 0.f};
#pragma unroll
    for (int j = 0; j < 9; ++j) {
        o.x = fmaf(w[j], X[j + 0], o.x);
        o.y = fmaf(w[j], X[j + 1], o.y);
        o.z = fmaf(w[j], X[j + 2], o.z);
        o.w = fmaf(w[j], X[j + 3], o.w);
    }
    return o;
}

// ---- phase task bodies (one task each; callers unroll statically) ----

template <bool G>
__device__ __forceinline__ void p1_task(int o, const float* __restrict__ xb,
                                        int oxf, int oy, const float* w,
                                        float4* __restrict__ h1) {
    int r = o / NH1, m = o % NH1;
    int gy = oy - 8 + r;
    float4 o4 = {0.f, 0.f, 0.f, 0.f};
    if (!G || (gy >= 0 && gy < HW)) {
        const float4* row = reinterpret_cast<const float4*>(xb + (size_t)gy * HW);
        float X[12];
#pragma unroll
        for (int k = 0; k < 3; ++k) {
            int g4 = oxf - 2 + m + k;
            float4 v;
            if (G) v = (g4 >= 0 && g4 < HW4) ? row[g4] : float4{0.f, 0.f, 0.f, 0.f};
            else   v = row[g4];
            X[4 * k + 0] = v.x; X[4 * k + 1] = v.y;
            X[4 * k + 2] = v.z; X[4 * k + 3] = v.w;
        }
        o4 = conv9(X, w);
    }
    h1[o] = o4;
}

template <bool G>
__device__ __forceinline__ void p2_task(int t, const float* __restrict__ xb,
                                        int oxf, int oy, const float* w,
                                        const float4* __restrict__ h1,
                                        float4* __restrict__ dd) {
    int r = t / NH1, m = t % NH1;
    int gy = oy - 4 + r;
    int g4 = oxf - 1 + m;
    // issue the global load FIRST so vmem overlaps the 9 LDS taps
    bool xin = !G || (gy >= 0 && gy < HW && g4 >= 0 && g4 < HW4);
    float4 xv = {0.f, 0.f, 0.f, 0.f};
    if (xin) xv = reinterpret_cast<const float4*>(xb + (size_t)gy * HW)[g4];
    float4 mean = {0.f, 0.f, 0.f, 0.f};
#pragma unroll
    for (int j = 0; j < 9; ++j) {
        const float4 h = h1[t + j * NH1];   // addr linear in tid + imm offset
        mean.x = fmaf(w[j], h.x, mean.x);
        mean.y = fmaf(w[j], h.y, mean.y);
        mean.z = fmaf(w[j], h.z, mean.z);
        mean.w = fmaf(w[j], h.w, mean.w);
    }
    float4 d = {0.f, 0.f, 0.f, 0.f};
    if (xin) {
        d.x = xv.x - mean.x; d.y = xv.y - mean.y;
        d.z = xv.z - mean.z; d.w = xv.w - mean.w;
    }
    dd[t] = d;
}

__device__ __forceinline__ void p3_task(int o, const float* w,
                                        const float4* __restrict__ dd,
                                        float4* __restrict__ h2) {
    int r = o / NH2, n = o % NH2;
    float4 a = dd[r * NH1 + n];
    float4 b = dd[r * NH1 + n + 1];
    float4 c = dd[r * NH1 + n + 2];
    float X[12] = {a.x * a.x, a.y * a.y, a.z * a.z, a.w * a.w,
                   b.x * b.x, b.y * b.y, b.z * b.z, b.w * b.w,
                   c.x * c.x, c.y * c.y, c.z * c.z, c.w * c.w};
    h2[o] = conv9(X, w);   // o == r*16 + n, contiguous
}

template <bool G>
__device__ __forceinline__ void run_tile(const float* __restrict__ xb,
                                         float* __restrict__ ob,
                                         int oxf, int oy, const float* w,
                                         float4* sm, int tid) {
    float4* h1 = sm;                 // [48][18]
    float4* dd = sm + RH1 * NH1;     // [40][18]
    float4* h2 = sm;                 // [40][16], aliases h1 (dead after p2)

    // ---- p1: 864 tasks = 3 sweeps + 96 tail ----
    p1_task<G>(tid,       xb, oxf, oy, w, h1);
    p1_task<G>(tid + 256, xb, oxf, oy, w, h1);
    p1_task<G>(tid + 512, xb, oxf, oy, w, h1);
    if (tid < 96) p1_task<G>(tid + 768, xb, oxf, oy, w, h1);
    __syncthreads();

    // ---- p2: 720 tasks = 2 sweeps + 208 tail ----
    p2_task<G>(tid,       xb, oxf, oy, w, h1, dd);
    p2_task<G>(tid + 256, xb, oxf, oy, w, h1, dd);
    if (tid < 208) p2_task<G>(tid + 512, xb, oxf, oy, w, h1, dd);
    __syncthreads();

    // ---- p3: 640 tasks = 2 sweeps + 128 tail ----
    p3_task(tid,       w, dd, h2);
    p3_task(tid + 256, w, dd, h2);
    if (tid < 128) p3_task(tid + 512, w, dd, h2);
    __syncthreads();

    // ---- p4: n2 = v-conv(h2); out = keep ? dd/sqrt(n2) : dd ----
    // 512 outputs: n = tid%16 (group-consecutive), 16 row-groups of 2.
    {
        int n = tid % NH2, rg = tid / NH2;
        int r0 = rg * 2;
        float4 ring[9];
#pragma unroll
        for (int i = 0; i < 9; ++i) ring[i] = h2[(r0 + i) * NH2 + n];
#pragma unroll
        for (int k = 0; k < 2; ++k) {
            if (k) ring[(k + 8) % 9] = h2[(r0 + 8 + k) * NH2 + n];
            float4 n2 = {0.f, 0.f, 0.f, 0.f};
#pragma unroll
            for (int j = 0; j < 9; ++j) {
                const float4 h = ring[(k + j) % 9];
                n2.x = fmaf(w[j], h.x, n2.x);
                n2.y = fmaf(w[j], h.y, n2.y);
                n2.z = fmaf(w[j], h.z, n2.z);
                n2.w = fmaf(w[j], h.w, n2.w);
            }
            float4 dv = dd[(r0 + k + 4) * NH1 + n + 1];
            nf4 o;  // keep <=> sqrt(n2) > 0.5 <=> n2 > 0.25
            { float nr = rsqrtf(n2.x); o.x = (n2.x > 0.25f) ? dv.x * nr : dv.x; }
            { float nr = rsqrtf(n2.y); o.y = (n2.y > 0.25f) ? dv.y * nr : dv.y; }
            { float nr = rsqrtf(n2.z); o.z = (n2.z > 0.25f) ? dv.z * nr : dv.z; }
            { float nr = rsqrtf(n2.w); o.w = (n2.w > 0.25f) ? dv.w * nr : dv.w; }
            __builtin_nontemporal_store(o,
                reinterpret_cast<nf4*>(ob + (size_t)(oy + r0 + k) * HW) + oxf + n);
        }
    }
}

__global__ __launch_bounds__(256, 6) void lcn_kernel(const float* __restrict__ x,
                                                     float* __restrict__ out,
                                                     W9 wts) {
    __shared__ float4 sm[RH1 * NH1 + RDD * NH1];  // 25,344 B

    const int tid = threadIdx.x;
    const int oxf = blockIdx.x * NH2;
    const int oy  = blockIdx.y * TSY;
    const float* xb = x + (size_t)blockIdx.z * HW * HW;
    float* ob = out + (size_t)blockIdx.z * HW * HW;

    float w[9];
#pragma unroll
    for (int i = 0; i < 9; ++i) w[i] = wts.w[i];

    // interior: x-ranges [oxf-2, oxf+19] f4 and y [oy-8, oy+39] provably
    // in-image for bx in 1..6, by in 1..14.
    const bool interior = (blockIdx.x > 0 && blockIdx.x < gridDim.x - 1 &&
                           blockIdx.y > 0 && blockIdx.y < gridDim.y - 1);
    if (interior) run_tile<false>(xb, ob, oxf, oy, w, sm, tid);
    else          run_tile<true >(xb, ob, oxf, oy, w, sm, tid);
}

static W9 make_w() {
    // reference: sigmah = 9/6, exponent divides by 2*sigmah = 3.0;
    // taps centered at 4.5 (asymmetric); separable: w1 = g1 / sum(g1).
    double g[9], s = 0.0;
    for (int i = 0; i < 9; ++i) {
        double off = (double)i - 4.5;
        g[i] = exp(-(off * off) / 3.0);
        s += g[i];
    }
    W9 r;
    for (int i = 0; i < 9; ++i) r.w[i] = (float)(g[i] / s);
    return r;
}

extern "C" void kernel_launch(void* const* d_in, const int* in_sizes, int n_in,
                              void* d_out, int out_size, void* d_ws, size_t ws_size,
                              hipStream_t stream) {
    const float* x = (const float*)d_in[0];
    float* out = (float*)d_out;
    W9 w = make_w();
    dim3 grid(HW / 64, HW / TSY, 64);  // 8 x 16 x 64
    lcn_kernel<<<grid, dim3(256), 0, stream>>>(x, out, w);
}